// Round 1
// baseline (879.249 us; speedup 1.0000x reference)
//
#include <hip/hip_runtime.h>

#define T 512
constexpr int Bc = 512, Nc = 40, Hc = 128, FEc = 16, Mc = 128, H3 = 384, OUTc = 128, NPASS = 3;

__device__ __forceinline__ float fast_rcp(float x) { return __builtin_amdgcn_rcpf(x); }
__device__ __forceinline__ float fast_sigmoid(float x) { return fast_rcp(1.f + __expf(-x)); }
__device__ __forceinline__ float fast_tanh(float x) {
    float t = __expf(2.f * x);           // inf-safe: 1 - 2/(t+1) -> 1 as t->inf, -1 as t->0
    return 1.f - 2.f * fast_rcp(t + 1.f);
}

__global__ __launch_bounds__(T, 2) void mpnn_kernel(
    const float* __restrict__ nodes, const float* __restrict__ edges,
    const float* __restrict__ We, const float* __restrict__ Wn,
    const float* __restrict__ Wm, const float* __restrict__ Wi,
    const float* __restrict__ Wh, const float* __restrict__ bi,
    const float* __restrict__ bh, const float* __restrict__ Wg,
    const float* __restrict__ bg, const float* __restrict__ Wo,
    const float* __restrict__ bo, float* __restrict__ out)
{
    __shared__ float s_h[Nc][Hc];        // 20 KB  current hidden state
    __shared__ float s_np[Nc][Mc];       // 20 KB  nghb_proj; reused as h_new buffer
    __shared__ float s_emb[Nc][Mc];      // 20 KB  emb; reused as nodes at readout
    __shared__ float s_msg[Nc][Mc];      // 20 KB  messages
    __shared__ float s_wst[6144];        // 24 KB  weight k-chunk staging
    __shared__ float s_red[4][OUTc];     //  2 KB  readout partials
    __shared__ unsigned char s_nbr[Nc][Nc]; // adjacency, then compact neighbor lists
    __shared__ int s_cnt[Nc];

    const int b   = blockIdx.x;
    const int tid = threadIdx.x;
    const int m   = tid & 127;   // feature lane
    const int g   = tid >> 7;    // row group 0..3

    const float* nodes_b = nodes + (size_t)b * Nc * Hc;
    const float* edges_b = edges + (size_t)b * Nc * Nc * FEc;

    // Per-thread We column (m fixed for the whole kernel): no LDS in attention inner loop.
    float we[FEc];
#pragma unroll
    for (int f = 0; f < FEc; ++f) we[f] = We[f * Mc + m];

    const float bias_r  = bi[m] + bh[m];
    const float bias_z  = bi[Mc + m] + bh[Mc + m];
    const float bias_in = bi[2 * Mc + m];
    const float bias_hn = bh[2 * Mc + m];

    // h <- nodes
    for (int idx = tid; idx < Nc * Hc / 4; idx += T)
        ((float4*)s_h)[idx] = ((const float4*)nodes_b)[idx];

    // adjacency: edge-feature rows are exactly zero where no edge
    for (int p = tid; p < Nc * Nc; p += T) {
        const float4* e4 = (const float4*)(edges_b + p * FEc);
        float4 a0 = e4[0], a1 = e4[1], a2 = e4[2], a3 = e4[3];
        float s = a0.x + a0.y + a0.z + a0.w + a1.x + a1.y + a1.z + a1.w
                + a2.x + a2.y + a2.z + a2.w + a3.x + a3.y + a3.z + a3.w;
        ((unsigned char*)s_nbr)[p] = (s > 0.f) ? 1 : 0;
    }
    __syncthreads();
    if (tid < Nc) {       // compact in place: write pos <= read pos
        int c = 0;
#pragma unroll 1
        for (int j = 0; j < Nc; ++j)
            if (s_nbr[tid][j]) { s_nbr[tid][c] = (unsigned char)j; ++c; }
        s_cnt[tid] = c;
    }
    __syncthreads();

    for (int pass = 0; pass < NPASS; ++pass) {
        // ---------- Phase A: s_np = h@Wn, s_emb = h@Wm (k-chunked weight staging) ----------
        float accN[10], accM[10];
#pragma unroll
        for (int jj = 0; jj < 10; ++jj) { accN[jj] = 0.f; accM[jj] = 0.f; }
        for (int kc = 0; kc < 8; ++kc) {
            const int k0 = kc * 16;
            __syncthreads();
            for (int idx = tid; idx < 2 * 16 * Mc; idx += T) {
                int mat = idx >> 11;
                int rem = idx & 2047;                 // kk*128+m
                const float* W = mat ? Wm : Wn;
                s_wst[idx] = W[k0 * Mc + rem];
            }
            __syncthreads();
#pragma unroll
            for (int kh = 0; kh < 4; ++kh) {
                float wn[4], wm[4];
#pragma unroll
                for (int t = 0; t < 4; ++t) {
                    wn[t] = s_wst[(kh * 4 + t) * Mc + m];
                    wm[t] = s_wst[2048 + (kh * 4 + t) * Mc + m];
                }
#pragma unroll
                for (int jj = 0; jj < 10; ++jj) {
                    int j = g + jj * 4;
                    float4 hv = *(const float4*)&s_h[j][k0 + kh * 4];
                    accN[jj] += hv.x * wn[0] + hv.y * wn[1] + hv.z * wn[2] + hv.w * wn[3];
                    accM[jj] += hv.x * wm[0] + hv.y * wm[1] + hv.z * wm[2] + hv.w * wm[3];
                }
            }
        }
        __syncthreads();
#pragma unroll
        for (int jj = 0; jj < 10; ++jj) {
            int j = g + jj * 4;
            s_np[j][m]  = accN[jj];
            s_emb[j][m] = accM[jj];
        }
        __syncthreads();

        // ---------- Attention: s_msg[i][m] = sum_j softmax_j(tanh(ep+np))*emb ----------
#pragma unroll 1
        for (int ib = 0; ib < 10; ++ib) {
            int i = g + ib * 4;
            int cnt = s_cnt[i];
            float pden = 0.f, pnum = 0.f;
            const float* erow = edges_b + i * Nc * FEc;
#pragma unroll 1
            for (int kn = 0; kn < cnt; ++kn) {
                int j = s_nbr[i][kn];
                const float4* ef = (const float4*)(erow + j * FEc);
                float4 a0 = ef[0], a1 = ef[1], a2 = ef[2], a3 = ef[3];
                float ep = a0.x*we[0] + a0.y*we[1] + a0.z*we[2] + a0.w*we[3]
                         + a1.x*we[4] + a1.y*we[5] + a1.z*we[6] + a1.w*we[7]
                         + a2.x*we[8] + a2.y*we[9] + a2.z*we[10]+ a2.w*we[11]
                         + a3.x*we[12]+ a3.y*we[13]+ a3.z*we[14]+ a3.w*we[15];
                float x = ep + s_np[j][m];
                float e = fast_tanh(x);
                float w = __expf(e);      // e in (-1,1): no max-subtraction needed
                pden += w;
                pnum += w * s_emb[j][m];
            }
            s_msg[i][m] = (cnt > 0) ? pnum * fast_rcp(pden) : 0.f;
        }
        __syncthreads();

        // ---------- GRU: fused gi/gh GEMMs, gates, masked h update ----------
        float ar[10], az[10], ain[10], ahn[10];
#pragma unroll
        for (int jj = 0; jj < 10; ++jj) { ar[jj] = bias_r; az[jj] = bias_z; ain[jj] = bias_in; ahn[jj] = bias_hn; }
        for (int kc = 0; kc < 16; ++kc) {
            const int k0 = kc * 8;
            __syncthreads();
            for (int idx = tid; idx < 2 * 8 * H3; idx += T) {
                int mat = (idx >= 3072);
                int rem = mat ? idx - 3072 : idx;     // kk*384+o
                const float* W = mat ? Wh : Wi;
                s_wst[idx] = W[k0 * H3 + rem];
            }
            __syncthreads();
#pragma unroll
            for (int kh = 0; kh < 2; ++kh) {
                float wir[4], wiz[4], win[4], whr[4], whz[4], whn[4];
#pragma unroll
                for (int t = 0; t < 4; ++t) {
                    int kk = kh * 4 + t;
                    wir[t] = s_wst[kk * H3 + m];
                    wiz[t] = s_wst[kk * H3 + Mc + m];
                    win[t] = s_wst[kk * H3 + 2 * Mc + m];
                    whr[t] = s_wst[3072 + kk * H3 + m];
                    whz[t] = s_wst[3072 + kk * H3 + Mc + m];
                    whn[t] = s_wst[3072 + kk * H3 + 2 * Mc + m];
                }
#pragma unroll
                for (int jj = 0; jj < 10; ++jj) {
                    int j = g + jj * 4;
                    float4 mv = *(const float4*)&s_msg[j][k0 + kh * 4];
                    float4 hv = *(const float4*)&s_h[j][k0 + kh * 4];
                    ar[jj]  += mv.x*wir[0] + mv.y*wir[1] + mv.z*wir[2] + mv.w*wir[3]
                             + hv.x*whr[0] + hv.y*whr[1] + hv.z*whr[2] + hv.w*whr[3];
                    az[jj]  += mv.x*wiz[0] + mv.y*wiz[1] + mv.z*wiz[2] + mv.w*wiz[3]
                             + hv.x*whz[0] + hv.y*whz[1] + hv.z*whz[2] + hv.w*whz[3];
                    ain[jj] += mv.x*win[0] + mv.y*win[1] + mv.z*win[2] + mv.w*win[3];
                    ahn[jj] += hv.x*whn[0] + hv.y*whn[1] + hv.z*whn[2] + hv.w*whn[3];
                }
            }
        }
#pragma unroll
        for (int jj = 0; jj < 10; ++jj) {
            int j = g + jj * 4;
            float r = fast_sigmoid(ar[jj]);
            float z = fast_sigmoid(az[jj]);
            float n = fast_tanh(ain[jj] + r * ahn[jj]);
            s_np[j][m] = (1.f - z) * n + z * s_h[j][m];   // h_new staged in s_np
        }
        __syncthreads();
        for (int idx = tid; idx < Nc * Hc; idx += T) {
            int j = idx >> 7;
            if (s_cnt[j] > 0) ((float*)s_h)[idx] = ((float*)s_np)[idx];
        }
        __syncthreads();
    }

    // ---------- Readout: out = sum_i mask * sigmoid(cat@Wg+bg) * (cat@Wo+bo) ----------
    {
        for (int idx = tid; idx < Nc * Hc / 4; idx += T)       // nodes into s_emb (cat tail)
            ((float4*)s_emb)[idx] = ((const float4*)nodes_b)[idx];

        float accG[10], accO[10];
        const float bgv = bg[m], bov = bo[m];
#pragma unroll
        for (int jj = 0; jj < 10; ++jj) { accG[jj] = bgv; accO[jj] = bov; }

        for (int kc = 0; kc < 16; ++kc) {
            const int k0 = kc * 16;   // over 2H=256; chunks never straddle the h/nodes split
            __syncthreads();
            for (int idx = tid; idx < 2 * 16 * OUTc; idx += T) {
                int mat = idx >> 11;
                int rem = idx & 2047;
                const float* W = mat ? Wo : Wg;
                s_wst[idx] = W[k0 * OUTc + rem];
            }
            __syncthreads();
            const bool hpart = (k0 < Hc);
            const int  kb    = hpart ? k0 : (k0 - Hc);
#pragma unroll
            for (int kh = 0; kh < 4; ++kh) {
                float wg[4], wo[4];
#pragma unroll
                for (int t = 0; t < 4; ++t) {
                    wg[t] = s_wst[(kh * 4 + t) * OUTc + m];
                    wo[t] = s_wst[2048 + (kh * 4 + t) * OUTc + m];
                }
#pragma unroll
                for (int jj = 0; jj < 10; ++jj) {
                    int j = g + jj * 4;
                    float4 cv = hpart ? *(const float4*)&s_h[j][kb + kh * 4]
                                      : *(const float4*)&s_emb[j][kb + kh * 4];
                    accG[jj] += cv.x*wg[0] + cv.y*wg[1] + cv.z*wg[2] + cv.w*wg[3];
                    accO[jj] += cv.x*wo[0] + cv.y*wo[1] + cv.z*wo[2] + cv.w*wo[3];
                }
            }
        }
        float psum = 0.f;
#pragma unroll
        for (int jj = 0; jj < 10; ++jj) {
            int j = g + jj * 4;
            if (s_cnt[j] > 0) {
                float gate = fast_sigmoid(accG[jj]);
                psum += gate * accO[jj];
            }
        }
        s_red[g][m] = psum;
        __syncthreads();
        if (tid < OUTc)
            out[(size_t)b * OUTc + tid] =
                s_red[0][tid] + s_red[1][tid] + s_red[2][tid] + s_red[3][tid];
    }
}

extern "C" void kernel_launch(void* const* d_in, const int* in_sizes, int n_in,
                              void* d_out, int out_size, void* d_ws, size_t ws_size,
                              hipStream_t stream) {
    const float* nodes = (const float*)d_in[0];
    const float* edges = (const float*)d_in[1];
    const float* We = (const float*)d_in[2];
    const float* Wn = (const float*)d_in[3];
    const float* Wm = (const float*)d_in[4];
    const float* Wi = (const float*)d_in[5];
    const float* Wh = (const float*)d_in[6];
    const float* bi = (const float*)d_in[7];
    const float* bh = (const float*)d_in[8];
    const float* Wg = (const float*)d_in[9];
    const float* bg = (const float*)d_in[10];
    const float* Wo = (const float*)d_in[11];
    const float* bo = (const float*)d_in[12];
    float* out = (float*)d_out;

    mpnn_kernel<<<Bc, T, 0, stream>>>(nodes, edges, We, Wn, Wm, Wi, Wh,
                                      bi, bh, Wg, bg, Wo, bo, out);
}

// Round 2
// 363.994 us; speedup vs baseline: 2.4156x; 2.4156x over previous
//
#include <hip/hip_runtime.h>

#define T 512
constexpr int Bc = 512, Nc = 40, Hc = 128, FEc = 16, Mc = 128, H3 = 384, OUTc = 128, NPASS = 3;
constexpr int ROWP = 136;   // bf16 LDS row pitch (pad breaks 16-way bank conflict on A-frag reads)
constexpr int HP   = 132;   // fp32 h row pitch

typedef __attribute__((ext_vector_type(8))) short short8;
typedef __attribute__((ext_vector_type(4))) float floatx4;

// ws layout (bf16 elements): fragment-major B operands
constexpr int WS_WN = 0;        // 128x128 -> 16384
constexpr int WS_WM = 16384;
constexpr int WS_WI = 32768;    // 128x384 -> 49152
constexpr int WS_WH = 81920;
constexpr int WS_WG = 131072;   // 256x128 -> 32768
constexpr int WS_WO = 163840;   // end 196608 elems = 384 KB

__device__ __forceinline__ float fast_rcp(float x) { return __builtin_amdgcn_rcpf(x); }
__device__ __forceinline__ float fast_sigmoid(float x) { return fast_rcp(1.f + __expf(-x)); }
__device__ __forceinline__ float fast_tanh(float x) {
    float t = __expf(2.f * x);
    return 1.f - 2.f * fast_rcp(t + 1.f);
}
__device__ __forceinline__ float bf2f(unsigned short u) {
    union { unsigned int i; float f; } v; v.i = ((unsigned int)u) << 16; return v.f;
}
__device__ __forceinline__ unsigned short f2bf(float f) {
    union { float f; unsigned int i; } v; v.f = f;
    unsigned int r = v.i + 0x7fff + ((v.i >> 16) & 1);   // RNE
    return (unsigned short)(r >> 16);
}

__device__ __forceinline__ floatx4 mm(short8 a, short8 b, floatx4 c) {
    return __builtin_amdgcn_mfma_f32_16x16x32_bf16(a, b, c, 0, 0, 0);
}
// A-fragment from LDS bf16 buffer: A[m=lane&15][k=quad*8+j]; rows>=40 clamped (their C rows are discarded)
__device__ __forceinline__ short8 afrag(const unsigned short* buf, int mt, int kt, int lane) {
    int row = mt * 16 + (lane & 15); row = row > 39 ? 39 : row;
    return *(const short8*)(buf + row * ROWP + kt * 32 + (lane >> 4) * 8);
}
// B-fragment from global frag buffer
__device__ __forceinline__ short8 bfrag(const unsigned short* w, int nt, int nKT, int kt, int lane) {
    return *(const short8*)(w + ((nt * nKT + kt) * 64 + lane) * 8);
}

// ---- prep: weights -> bf16 B-fragment layout in ws ----
__global__ void prep_kernel(const float* __restrict__ Wn, const float* __restrict__ Wm,
                            const float* __restrict__ Wi, const float* __restrict__ Wh,
                            const float* __restrict__ Wg, const float* __restrict__ Wo,
                            unsigned short* __restrict__ ws) {
    int c = blockIdx.x, lane = threadIdx.x;
    const float* W; int N, nKT, local; unsigned short* dst;
    if (c < 32)       { W = Wn; N = 128; nKT = 4; local = c;       dst = ws + WS_WN; }
    else if (c < 64)  { W = Wm; N = 128; nKT = 4; local = c - 32;  dst = ws + WS_WM; }
    else if (c < 160) { W = Wi; N = 384; nKT = 4; local = c - 64;  dst = ws + WS_WI; }
    else if (c < 256) { W = Wh; N = 384; nKT = 4; local = c - 160; dst = ws + WS_WH; }
    else if (c < 320) { W = Wg; N = 128; nKT = 8; local = c - 256; dst = ws + WS_WG; }
    else              { W = Wo; N = 128; nKT = 8; local = c - 320; dst = ws + WS_WO; }
    int nt = local / nKT, kt = local % nKT;
    int quad = lane >> 4, l16 = lane & 15;
    unsigned short tmp[8];
#pragma unroll
    for (int j = 0; j < 8; ++j) {
        int k = kt * 32 + quad * 8 + j;
        tmp[j] = f2bf(W[k * N + nt * 16 + l16]);
    }
    *(short8*)(dst + local * 512 + lane * 8) = *(short8*)tmp;
}

__global__ __launch_bounds__(T, 4) void mpnn_kernel(
    const float* __restrict__ nodes, const float* __restrict__ edges,
    const float* __restrict__ We, const float* __restrict__ bi,
    const float* __restrict__ bh, const float* __restrict__ bg,
    const float* __restrict__ bo, const unsigned short* __restrict__ ws,
    float* __restrict__ out)
{
    __shared__ float s_h[Nc * HP];                                  // 21.1 KB fp32 hidden state
    __shared__ __attribute__((aligned(16))) unsigned short s_hb[Nc * ROWP];  // bf16 h
    __shared__ __attribute__((aligned(16))) unsigned short s_mb[Nc * ROWP];  // bf16 messages / nodes(cat)
    __shared__ __attribute__((aligned(16))) unsigned short s_npb[Nc * ROWP]; // bf16 nghb_proj
    __shared__ __attribute__((aligned(16))) unsigned short s_eb[Nc * ROWP];  // bf16 emb
    __shared__ __attribute__((aligned(16))) unsigned short s_r[Nc * ROWP];   // bf16 r gate
    __shared__ unsigned char s_nbr[Nc][Nc];
    __shared__ int s_cnt[Nc];
    __shared__ float s_out[OUTc];

    const int b = blockIdx.x, tid = threadIdx.x;
    const int lane = tid & 63, wave = tid >> 6;
    const int quad = lane >> 4, l16 = lane & 15;
    const int m = tid & 127, g = tid >> 7;   // attention mapping

    const float* nodes_b = nodes + (size_t)b * Nc * Hc;
    const float* edges_b = edges + (size_t)b * Nc * Nc * FEc;
    const unsigned short* wWn = ws + WS_WN; const unsigned short* wWm = ws + WS_WM;
    const unsigned short* wWi = ws + WS_WI; const unsigned short* wWh = ws + WS_WH;
    const unsigned short* wWg = ws + WS_WG; const unsigned short* wWo = ws + WS_WO;

    float we[FEc];
#pragma unroll
    for (int f = 0; f < FEc; ++f) we[f] = We[f * Mc + m];

    // init h (fp32 + bf16)
    for (int idx = tid; idx < Nc * Hc; idx += T) {
        int row = idx >> 7, col = idx & 127;
        float v = nodes_b[idx];
        s_h[row * HP + col] = v;
        s_hb[row * ROWP + col] = f2bf(v);
    }
    // adjacency from edge-feature sums
    for (int p = tid; p < Nc * Nc; p += T) {
        const float4* e4 = (const float4*)(edges_b + p * FEc);
        float4 a0 = e4[0], a1 = e4[1], a2 = e4[2], a3 = e4[3];
        float s = a0.x + a0.y + a0.z + a0.w + a1.x + a1.y + a1.z + a1.w
                + a2.x + a2.y + a2.z + a2.w + a3.x + a3.y + a3.z + a3.w;
        ((unsigned char*)s_nbr)[p] = (s > 0.f) ? 1 : 0;
    }
    __syncthreads();
    if (tid < Nc) {
        int c = 0;
#pragma unroll 1
        for (int j = 0; j < Nc; ++j)
            if (s_nbr[tid][j]) { s_nbr[tid][c] = (unsigned char)j; ++c; }
        s_cnt[tid] = c;
    }
    __syncthreads();

    for (int pass = 0; pass < NPASS; ++pass) {
        // ---- Phase A: np = h@Wn, emb = h@Wm (MFMA) ----
        for (int t = wave; t < 48; t += 8) {
            int nt = t & 7, mt = (t >> 3) % 3, mat = t / 24;
            const unsigned short* wb = mat ? wWm : wWn;
            floatx4 acc = {0.f, 0.f, 0.f, 0.f};
#pragma unroll
            for (int kt = 0; kt < 4; ++kt)
                acc = mm(afrag(s_hb, mt, kt, lane), bfrag(wb, nt, 4, kt, lane), acc);
            unsigned short* dst = mat ? s_eb : s_npb;
            int col = nt * 16 + l16;
#pragma unroll
            for (int reg = 0; reg < 4; ++reg) {
                int row = mt * 16 + quad * 4 + reg;
                if (row < Nc) dst[row * ROWP + col] = f2bf(acc[reg]);
            }
        }
        __syncthreads();

        // ---- Attention (VALU, sparse) ----
#pragma unroll 1
        for (int ib = 0; ib < 10; ++ib) {
            int i = g + ib * 4;
            int cnt = s_cnt[i];
            float pden = 0.f, pnum = 0.f;
            const float* erow = edges_b + i * Nc * FEc;
#pragma unroll 1
            for (int kn = 0; kn < cnt; ++kn) {
                int j = s_nbr[i][kn];
                const float4* ef = (const float4*)(erow + j * FEc);
                float4 a0 = ef[0], a1 = ef[1], a2 = ef[2], a3 = ef[3];
                float ep = a0.x*we[0] + a0.y*we[1] + a0.z*we[2] + a0.w*we[3]
                         + a1.x*we[4] + a1.y*we[5] + a1.z*we[6] + a1.w*we[7]
                         + a2.x*we[8] + a2.y*we[9] + a2.z*we[10]+ a2.w*we[11]
                         + a3.x*we[12]+ a3.y*we[13]+ a3.z*we[14]+ a3.w*we[15];
                float x = ep + bf2f(s_npb[j * ROWP + m]);
                float w = __expf(fast_tanh(x));   // logits in (-1,1): no max-sub needed
                pden += w;
                pnum += w * bf2f(s_eb[j * ROWP + m]);
            }
            s_mb[i * ROWP + m] = f2bf((cnt > 0) ? pnum * fast_rcp(pden) : 0.f);
        }
        __syncthreads();

        // ---- GRU stage 1: r = sigmoid([msg,h]@[Wi;Wh] cols 0..127 + bias) ----
        for (int t = wave; t < 24; t += 8) {
            int nt = t & 7, mt = t >> 3;
            floatx4 acc = {0.f, 0.f, 0.f, 0.f};
#pragma unroll
            for (int kt = 0; kt < 4; ++kt)
                acc = mm(afrag(s_mb, mt, kt, lane), bfrag(wWi, nt, 4, kt, lane), acc);
#pragma unroll
            for (int kt = 0; kt < 4; ++kt)
                acc = mm(afrag(s_hb, mt, kt, lane), bfrag(wWh, nt, 4, kt, lane), acc);
            int col = nt * 16 + l16;
            float br = bi[col] + bh[col];
#pragma unroll
            for (int reg = 0; reg < 4; ++reg) {
                int row = mt * 16 + quad * 4 + reg;
                if (row < Nc) s_r[row * ROWP + col] = f2bf(fast_sigmoid(acc[reg] + br));
            }
        }
        __syncthreads();

        // ---- GRU stage 2: z, n, h_new (computed to regs; write after barrier) ----
        float hn[3][4];
        for (int tt = 0; tt < 3; ++tt) {
            int t = wave + tt * 8;
            int nt = t & 7, mt = t >> 3;
            floatx4 zacc = {0.f,0.f,0.f,0.f}, iacc = {0.f,0.f,0.f,0.f}, hacc = {0.f,0.f,0.f,0.f};
#pragma unroll
            for (int kt = 0; kt < 4; ++kt) {
                short8 am = afrag(s_mb, mt, kt, lane);
                short8 ah = afrag(s_hb, mt, kt, lane);
                zacc = mm(am, bfrag(wWi, nt + 8, 4, kt, lane), zacc);
                zacc = mm(ah, bfrag(wWh, nt + 8, 4, kt, lane), zacc);
                iacc = mm(am, bfrag(wWi, nt + 16, 4, kt, lane), iacc);
                hacc = mm(ah, bfrag(wWh, nt + 16, 4, kt, lane), hacc);
            }
            int col = nt * 16 + l16;
            float bz = bi[128 + col] + bh[128 + col];
            float bin = bi[256 + col], bhn = bh[256 + col];
#pragma unroll
            for (int reg = 0; reg < 4; ++reg) {
                int row = mt * 16 + quad * 4 + reg;
                if (row < Nc) {
                    float hold = s_h[row * HP + col];
                    if (s_cnt[row] > 0) {
                        float z = fast_sigmoid(zacc[reg] + bz);
                        float r = bf2f(s_r[row * ROWP + col]);
                        float n = fast_tanh(iacc[reg] + bin + r * (hacc[reg] + bhn));
                        hn[tt][reg] = (1.f - z) * n + z * hold;
                    } else hn[tt][reg] = hold;
                }
            }
        }
        __syncthreads();
        for (int tt = 0; tt < 3; ++tt) {
            int t = wave + tt * 8;
            int nt = t & 7, mt = t >> 3;
            int col = nt * 16 + l16;
#pragma unroll
            for (int reg = 0; reg < 4; ++reg) {
                int row = mt * 16 + quad * 4 + reg;
                if (row < Nc) {
                    s_h[row * HP + col] = hn[tt][reg];
                    s_hb[row * ROWP + col] = f2bf(hn[tt][reg]);
                }
            }
        }
        __syncthreads();
    }

    // ---- Readout: sum_i mask * sigmoid(cat@Wg+bg) * (cat@Wo+bo) ----
    for (int idx = tid; idx < Nc * Hc; idx += T) {
        int row = idx >> 7, col = idx & 127;
        s_mb[row * ROWP + col] = f2bf(nodes_b[idx]);   // cat tail
    }
    if (tid < OUTc) s_out[tid] = 0.f;
    __syncthreads();
    for (int t = wave; t < 24; t += 8) {
        int nt = t & 7, mt = t >> 3;
        floatx4 gacc = {0.f,0.f,0.f,0.f}, oacc = {0.f,0.f,0.f,0.f};
#pragma unroll
        for (int kt = 0; kt < 4; ++kt) {
            short8 a = afrag(s_hb, mt, kt, lane);
            gacc = mm(a, bfrag(wWg, nt, 8, kt, lane), gacc);
            oacc = mm(a, bfrag(wWo, nt, 8, kt, lane), oacc);
        }
#pragma unroll
        for (int kt = 0; kt < 4; ++kt) {
            short8 a = afrag(s_mb, mt, kt, lane);
            gacc = mm(a, bfrag(wWg, nt, 8, kt + 4, lane), gacc);
            oacc = mm(a, bfrag(wWo, nt, 8, kt + 4, lane), oacc);
        }
        int col = nt * 16 + l16;
        float bgv = bg[col], bov = bo[col], part = 0.f;
#pragma unroll
        for (int reg = 0; reg < 4; ++reg) {
            int row = mt * 16 + quad * 4 + reg;
            if (row < Nc && s_cnt[row] > 0)
                part += fast_sigmoid(gacc[reg] + bgv) * (oacc[reg] + bov);
        }
        atomicAdd(&s_out[col], part);
    }
    __syncthreads();
    if (tid < OUTc) out[(size_t)b * OUTc + tid] = s_out[tid];
}

extern "C" void kernel_launch(void* const* d_in, const int* in_sizes, int n_in,
                              void* d_out, int out_size, void* d_ws, size_t ws_size,
                              hipStream_t stream) {
    const float* nodes = (const float*)d_in[0];
    const float* edges = (const float*)d_in[1];
    const float* We = (const float*)d_in[2];
    const float* Wn = (const float*)d_in[3];
    const float* Wm = (const float*)d_in[4];
    const float* Wi = (const float*)d_in[5];
    const float* Wh = (const float*)d_in[6];
    const float* bi = (const float*)d_in[7];
    const float* bh = (const float*)d_in[8];
    const float* Wg = (const float*)d_in[9];
    const float* bg = (const float*)d_in[10];
    const float* Wo = (const float*)d_in[11];
    const float* bo = (const float*)d_in[12];
    float* out = (float*)d_out;
    unsigned short* ws = (unsigned short*)d_ws;

    prep_kernel<<<384, 64, 0, stream>>>(Wn, Wm, Wi, Wh, Wg, Wo, ws);
    mpnn_kernel<<<Bc, T, 0, stream>>>(nodes, edges, We, bi, bh, bg, bo, ws, out);
}

// Round 4
// 316.631 us; speedup vs baseline: 2.7769x; 1.1496x over previous
//
#include <hip/hip_runtime.h>

#define T 512
constexpr int Bc = 512, Nc = 40, Hc = 128, FEc = 16, Mc = 128, OUTc = 128, NPASS = 3;
constexpr int ROWP = 136;    // bf16 LDS row pitch: 16 rows x ds_read_b128 -> 2-way bank alias (free)
constexpr int EPOOL = 1024;  // edge pool slots (mean ~296; fallback handles overflow)

typedef __attribute__((ext_vector_type(8))) short short8;
typedef __attribute__((ext_vector_type(4))) float floatx4;
typedef __attribute__((ext_vector_type(4))) float fvec4;   // native vec for nontemporal builtins

// ws layout (bf16 elements): fragment-major B operands
constexpr int WS_WN = 0, WS_WM = 16384, WS_WI = 32768, WS_WH = 81920, WS_WG = 131072, WS_WO = 163840;

__device__ __forceinline__ float fast_rcp(float x) { return __builtin_amdgcn_rcpf(x); }
__device__ __forceinline__ float fast_sigmoid(float x) { return fast_rcp(1.f + __expf(-x)); }
__device__ __forceinline__ float fast_tanh(float x) {
    float t = __expf(2.f * x);
    return 1.f - 2.f * fast_rcp(t + 1.f);
}
__device__ __forceinline__ float bf2f(unsigned short u) {
    union { unsigned int i; float f; } v; v.i = ((unsigned int)u) << 16; return v.f;
}
__device__ __forceinline__ unsigned short f2bf(float f) {
    union { float f; unsigned int i; } v; v.f = f;
    unsigned int r = v.i + 0x7fff + ((v.i >> 16) & 1);   // RNE
    return (unsigned short)(r >> 16);
}
__device__ __forceinline__ float bflo(unsigned int d) {
    union { unsigned int i; float f; } v; v.i = d << 16; return v.f;
}
__device__ __forceinline__ float bfhi(unsigned int d) {
    union { unsigned int i; float f; } v; v.i = d & 0xffff0000u; return v.f;
}

__device__ __forceinline__ floatx4 mm(short8 a, short8 b, floatx4 c) {
    return __builtin_amdgcn_mfma_f32_16x16x32_bf16(a, b, c, 0, 0, 0);
}
// A-fragment from LDS bf16 buffer: A[m=lane&15][k=quad*8+j]; rows>=40 clamped (their C rows discarded)
__device__ __forceinline__ short8 afrag(const unsigned short* buf, int mt, int kt, int lane) {
    int row = mt * 16 + (lane & 15); row = row > 39 ? 39 : row;
    return *(const short8*)(buf + row * ROWP + kt * 32 + (lane >> 4) * 8);
}
// B-fragment from global frag buffer (L2-resident)
__device__ __forceinline__ short8 bfrag(const unsigned short* w, int nt, int nKT, int kt, int lane) {
    return *(const short8*)(w + ((nt * nKT + kt) * 64 + lane) * 8);
}

// ---- prep: weights -> bf16 B-fragment layout in ws ----
__global__ void prep_kernel(const float* __restrict__ Wn, const float* __restrict__ Wm,
                            const float* __restrict__ Wi, const float* __restrict__ Wh,
                            const float* __restrict__ Wg, const float* __restrict__ Wo,
                            unsigned short* __restrict__ ws) {
    int c = blockIdx.x, lane = threadIdx.x;
    const float* W; int N, nKT, local; unsigned short* dst;
    if (c < 32)       { W = Wn; N = 128; nKT = 4; local = c;       dst = ws + WS_WN; }
    else if (c < 64)  { W = Wm; N = 128; nKT = 4; local = c - 32;  dst = ws + WS_WM; }
    else if (c < 160) { W = Wi; N = 384; nKT = 4; local = c - 64;  dst = ws + WS_WI; }
    else if (c < 256) { W = Wh; N = 384; nKT = 4; local = c - 160; dst = ws + WS_WH; }
    else if (c < 320) { W = Wg; N = 128; nKT = 8; local = c - 256; dst = ws + WS_WG; }
    else              { W = Wo; N = 128; nKT = 8; local = c - 320; dst = ws + WS_WO; }
    int nt = local / nKT, kt = local % nKT;
    int quad = lane >> 4, l16 = lane & 15;
    short8 v;
#pragma unroll
    for (int j = 0; j < 8; ++j) {
        int k = kt * 32 + quad * 8 + j;
        v[j] = (short)f2bf(W[k * N + nt * 16 + l16]);
    }
    *(short8*)(dst + local * 512 + lane * 8) = v;
}

__global__ __launch_bounds__(T, 4) void mpnn_kernel(
    const float* __restrict__ nodes, const float* __restrict__ edges,
    const float* __restrict__ We, const float* __restrict__ bi,
    const float* __restrict__ bh, const float* __restrict__ bg,
    const float* __restrict__ bo, const unsigned short* __restrict__ ws,
    float* __restrict__ out)
{
    __shared__ __attribute__((aligned(16))) unsigned short s_hb[Nc * ROWP];   // bf16 h
    __shared__ __attribute__((aligned(16))) unsigned short s_mb[Nc * ROWP];   // bf16 messages / nodes(cat)
    __shared__ __attribute__((aligned(16))) unsigned short s_npb[Nc * ROWP];  // bf16 nghb_proj (init: slot_src tmp)
    __shared__ __attribute__((aligned(16))) unsigned short s_eb[Nc * ROWP];   // bf16 emb
    __shared__ __attribute__((aligned(16))) unsigned short s_pool[EPOOL * FEc]; // 32 KB compact edge features
    __shared__ unsigned char s_nbr[Nc][Nc];
    __shared__ int s_cnt[Nc];
    __shared__ int s_off[Nc];
    __shared__ int s_total;

    const int b = blockIdx.x, tid = threadIdx.x;
    const int lane = tid & 63, wave = tid >> 6;
    const int quad = lane >> 4, l16 = lane & 15;
    const int m = tid & 127, g = tid >> 7;   // attention mapping
    const int col = wave * 16 + l16;         // this thread's output column for all GEMMs

    const float* nodes_b = nodes + (size_t)b * Nc * Hc;
    const float* edges_b = edges + (size_t)b * Nc * Nc * FEc;
    const unsigned short* wWn = ws + WS_WN; const unsigned short* wWm = ws + WS_WM;
    const unsigned short* wWi = ws + WS_WI; const unsigned short* wWh = ws + WS_WH;
    const unsigned short* wWg = ws + WS_WG; const unsigned short* wWo = ws + WS_WO;

    // ---- init: fp32 h lives in registers (static (row,col)<->thread map), bf16 copy in LDS ----
    float hreg[3][4];
#pragma unroll
    for (int mt = 0; mt < 3; ++mt)
#pragma unroll
        for (int reg = 0; reg < 4; ++reg) {
            int row = mt * 16 + quad * 4 + reg;
            float v = (row < Nc) ? nodes_b[row * Hc + col] : 0.f;
            hreg[mt][reg] = v;
            if (row < Nc) s_hb[row * ROWP + col] = f2bf(v);
        }

    // ---- adjacency scan (streaming, non-temporal: don't evict L2-resident weights) ----
    for (int p = tid; p < Nc * Nc; p += T) {
        const fvec4* e4 = (const fvec4*)(edges_b + p * FEc);
        fvec4 a0 = __builtin_nontemporal_load(e4);
        fvec4 a1 = __builtin_nontemporal_load(e4 + 1);
        fvec4 a2 = __builtin_nontemporal_load(e4 + 2);
        fvec4 a3 = __builtin_nontemporal_load(e4 + 3);
        float s = a0.x + a0.y + a0.z + a0.w + a1.x + a1.y + a1.z + a1.w
                + a2.x + a2.y + a2.z + a2.w + a3.x + a3.y + a3.z + a3.w;
        ((unsigned char*)s_nbr)[p] = (s > 0.f) ? 1 : 0;
    }
    __syncthreads();
    if (tid < Nc) {               // compact neighbor list in place
        int c = 0;
#pragma unroll 1
        for (int j = 0; j < Nc; ++j)
            if (s_nbr[tid][j]) { s_nbr[tid][c] = (unsigned char)j; ++c; }
        s_cnt[tid] = c;
    }
    __syncthreads();
    if (tid == 0) {               // prefix-sum edge offsets
        int tot = 0;
#pragma unroll 1
        for (int i = 0; i < Nc; ++i) { s_off[i] = tot; tot += s_cnt[i]; }
        s_total = tot;
    }
    __syncthreads();
    int* slot_src = (int*)s_npb;  // temp alias; overwritten by Phase A of pass 0
    if (tid < Nc) {
        int base = s_off[tid], cnt = s_cnt[tid];
#pragma unroll 1
        for (int kn = 0; kn < cnt; ++kn) {
            int slot = base + kn;
            if (slot < EPOOL) slot_src[slot] = tid * Nc + s_nbr[tid][kn];
        }
    }
    __syncthreads();
    {   // fill compact bf16 edge pool
        int E = s_total < EPOOL ? s_total : EPOOL;
#pragma unroll 1
        for (int w = tid; w < E * 2; w += T) {
            int s = w >> 1, hf = w & 1;
            const float* src = edges_b + (size_t)slot_src[s] * FEc + hf * 8;
            fvec4 x = __builtin_nontemporal_load((const fvec4*)src);
            fvec4 y = __builtin_nontemporal_load((const fvec4*)(src + 4));
            short8 v;
            v[0] = (short)f2bf(x.x); v[1] = (short)f2bf(x.y); v[2] = (short)f2bf(x.z); v[3] = (short)f2bf(x.w);
            v[4] = (short)f2bf(y.x); v[5] = (short)f2bf(y.y); v[6] = (short)f2bf(y.z); v[7] = (short)f2bf(y.w);
            *(short8*)(s_pool + s * FEc + hf * 8) = v;
        }
    }
    __syncthreads();

    for (int pass = 0; pass < NPASS; ++pass) {
        // ---- Phase A: np = h@Wn, emb = h@Wm (B-frags held in regs, reused across 3 m-tiles) ----
#pragma unroll
        for (int jb = 0; jb < 2; ++jb) {
            const unsigned short* wb = jb ? wWm : wWn;
            unsigned short* dst = jb ? s_eb : s_npb;
            short8 bfr[4];
#pragma unroll
            for (int kt = 0; kt < 4; ++kt) bfr[kt] = bfrag(wb, wave, 4, kt, lane);
#pragma unroll
            for (int mt = 0; mt < 3; ++mt) {
                floatx4 acc = {0.f, 0.f, 0.f, 0.f};
#pragma unroll
                for (int kt = 0; kt < 4; ++kt) acc = mm(afrag(s_hb, mt, kt, lane), bfr[kt], acc);
#pragma unroll
                for (int reg = 0; reg < 4; ++reg) {
                    int row = mt * 16 + quad * 4 + reg;
                    if (row < Nc) dst[row * ROWP + col] = f2bf(acc[reg]);
                }
            }
        }
        __syncthreads();

        // ---- Attention (VALU, sparse, LDS edge pool) ----
        float wef[FEc];
#pragma unroll
        for (int f = 0; f < FEc; ++f) wef[f] = We[f * Mc + m];
#pragma unroll 1
        for (int ib = 0; ib < 10; ++ib) {
            int i = g + ib * 4;
            int cnt = s_cnt[i], base = s_off[i];
            float pden = 0.f, pnum = 0.f;
#pragma unroll 1
            for (int kn = 0; kn < cnt; ++kn) {
                int j = s_nbr[i][kn];
                int slot = base + kn;
                float ep;
                if (slot < EPOOL) {     // wave-uniform branch
                    const unsigned int* e = (const unsigned int*)(s_pool + slot * FEc);
                    uint4 p0 = *(const uint4*)e;
                    uint4 p1 = *(const uint4*)(e + 4);
                    ep = bflo(p0.x)*wef[0]  + bfhi(p0.x)*wef[1]
                       + bflo(p0.y)*wef[2]  + bfhi(p0.y)*wef[3]
                       + bflo(p0.z)*wef[4]  + bfhi(p0.z)*wef[5]
                       + bflo(p0.w)*wef[6]  + bfhi(p0.w)*wef[7]
                       + bflo(p1.x)*wef[8]  + bfhi(p1.x)*wef[9]
                       + bflo(p1.y)*wef[10] + bfhi(p1.y)*wef[11]
                       + bflo(p1.z)*wef[12] + bfhi(p1.z)*wef[13]
                       + bflo(p1.w)*wef[14] + bfhi(p1.w)*wef[15];
                } else {                // pool overflow fallback (statistically never)
                    const float4* ef = (const float4*)(edges_b + ((size_t)i * Nc + j) * FEc);
                    float4 a0 = ef[0], a1 = ef[1], a2 = ef[2], a3 = ef[3];
                    ep = a0.x*wef[0] + a0.y*wef[1] + a0.z*wef[2] + a0.w*wef[3]
                       + a1.x*wef[4] + a1.y*wef[5] + a1.z*wef[6] + a1.w*wef[7]
                       + a2.x*wef[8] + a2.y*wef[9] + a2.z*wef[10]+ a2.w*wef[11]
                       + a3.x*wef[12]+ a3.y*wef[13]+ a3.z*wef[14]+ a3.w*wef[15];
                }
                float x = ep + bf2f(s_npb[j * ROWP + m]);
                float w = __expf(fast_tanh(x));   // logits in (-1,1): no max-sub needed
                pden += w;
                pnum += w * bf2f(s_eb[j * ROWP + m]);
            }
            s_mb[i * ROWP + m] = f2bf((cnt > 0) ? pnum * fast_rcp(pden) : 0.f);
        }
        __syncthreads();

        // ---- GRU: single fused kt-loop, all 4 accumulator sets, r stays in registers ----
        floatx4 racc[3], zacc[3], iacc[3], hacc[3];
#pragma unroll
        for (int mt = 0; mt < 3; ++mt) {
            racc[mt] = {0.f,0.f,0.f,0.f}; zacc[mt] = {0.f,0.f,0.f,0.f};
            iacc[mt] = {0.f,0.f,0.f,0.f}; hacc[mt] = {0.f,0.f,0.f,0.f};
        }
#pragma unroll
        for (int kt = 0; kt < 4; ++kt) {
            short8 bir = bfrag(wWi, wave,      4, kt, lane);
            short8 bhr = bfrag(wWh, wave,      4, kt, lane);
            short8 biz = bfrag(wWi, wave + 8,  4, kt, lane);
            short8 bhz = bfrag(wWh, wave + 8,  4, kt, lane);
            short8 bin8 = bfrag(wWi, wave + 16, 4, kt, lane);
            short8 bhn8 = bfrag(wWh, wave + 16, 4, kt, lane);
#pragma unroll
            for (int mt = 0; mt < 3; ++mt) {
                short8 am = afrag(s_mb, mt, kt, lane);
                short8 ah = afrag(s_hb, mt, kt, lane);
                racc[mt] = mm(am, bir, racc[mt]);  racc[mt] = mm(ah, bhr, racc[mt]);
                zacc[mt] = mm(am, biz, zacc[mt]);  zacc[mt] = mm(ah, bhz, zacc[mt]);
                iacc[mt] = mm(am, bin8, iacc[mt]); hacc[mt] = mm(ah, bhn8, hacc[mt]);
            }
        }
        float br  = bi[col] + bh[col];
        float bz  = bi[Mc + col] + bh[Mc + col];
        float bnI = bi[2 * Mc + col];
        float bnH = bh[2 * Mc + col];
        float hn[3][4];
#pragma unroll
        for (int mt = 0; mt < 3; ++mt)
#pragma unroll
            for (int reg = 0; reg < 4; ++reg) {
                int row = mt * 16 + quad * 4 + reg;
                float hold = hreg[mt][reg];
                float r = fast_sigmoid(racc[mt][reg] + br);
                float z = fast_sigmoid(zacc[mt][reg] + bz);
                float n = fast_tanh(iacc[mt][reg] + bnI + r * (hacc[mt][reg] + bnH));
                float v = (1.f - z) * n + z * hold;
                hn[mt][reg] = (row < Nc && s_cnt[row] > 0) ? v : hold;
            }
        __syncthreads();   // all MFMA reads of s_hb/s_mb done before overwrite
#pragma unroll
        for (int mt = 0; mt < 3; ++mt)
#pragma unroll
            for (int reg = 0; reg < 4; ++reg) {
                int row = mt * 16 + quad * 4 + reg;
                hreg[mt][reg] = hn[mt][reg];
                if (row < Nc) s_hb[row * ROWP + col] = f2bf(hn[mt][reg]);
            }
        __syncthreads();
    }

    // ---- Readout: out = sum_i mask * sigmoid(cat@Wg+bg) * (cat@Wo+bo) ----
    for (int idx = tid; idx < Nc * Hc; idx += T) {
        int row = idx >> 7, c2 = idx & 127;
        s_mb[row * ROWP + c2] = f2bf(nodes_b[idx]);   // cat tail (messages dead)
    }
    __syncthreads();
    floatx4 gacc[3], oacc[3];
#pragma unroll
    for (int mt = 0; mt < 3; ++mt) { gacc[mt] = {0.f,0.f,0.f,0.f}; oacc[mt] = {0.f,0.f,0.f,0.f}; }
#pragma unroll
    for (int kt = 0; kt < 8; ++kt) {
        short8 bg8 = bfrag(wWg, wave, 8, kt, lane);
        short8 bo8 = bfrag(wWo, wave, 8, kt, lane);
#pragma unroll
        for (int mt = 0; mt < 3; ++mt) {
            short8 a = (kt < 4) ? afrag(s_hb, mt, kt, lane) : afrag(s_mb, mt, kt - 4, lane);
            gacc[mt] = mm(a, bg8, gacc[mt]);
            oacc[mt] = mm(a, bo8, oacc[mt]);
        }
    }
    float bgv = bg[col], bov = bo[col], psum = 0.f;
#pragma unroll
    for (int mt = 0; mt < 3; ++mt)
#pragma unroll
        for (int reg = 0; reg < 4; ++reg) {
            int row = mt * 16 + quad * 4 + reg;
            if (row < Nc && s_cnt[row] > 0)
                psum += fast_sigmoid(gacc[mt][reg] + bgv) * (oacc[mt][reg] + bov);
        }
    psum += __shfl_xor(psum, 16);   // reduce over the 4 quads sharing this col
    psum += __shfl_xor(psum, 32);
    if (quad == 0) out[(size_t)b * OUTc + col] = psum;
}

extern "C" void kernel_launch(void* const* d_in, const int* in_sizes, int n_in,
                              void* d_out, int out_size, void* d_ws, size_t ws_size,
                              hipStream_t stream) {
    const float* nodes = (const float*)d_in[0];
    const float* edges = (const float*)d_in[1];
    const float* We = (const float*)d_in[2];
    const float* Wn = (const float*)d_in[3];
    const float* Wm = (const float*)d_in[4];
    const float* Wi = (const float*)d_in[5];
    const float* Wh = (const float*)d_in[6];
    const float* bi = (const float*)d_in[7];
    const float* bh = (const float*)d_in[8];
    const float* Wg = (const float*)d_in[9];
    const float* bg = (const float*)d_in[10];
    const float* Wo = (const float*)d_in[11];
    const float* bo = (const float*)d_in[12];
    float* out = (float*)d_out;
    unsigned short* ws = (unsigned short*)d_ws;

    prep_kernel<<<384, 64, 0, stream>>>(Wn, Wm, Wi, Wh, Wg, Wo, ws);
    mpnn_kernel<<<Bc, T, 0, stream>>>(nodes, edges, We, bi, bh, bg, bo, ws, out);
}